// Round 1
// baseline (1401.371 us; speedup 1.0000x reference)
//
#include <hip/hip_runtime.h>

namespace {

constexpr int kB = 2048;        // windows
constexpr int kH = 8;           // heads
constexpr int kD = 64;          // dim head
constexpr int kM = 64;          // tokens per window
constexpr int kTableRows = 16129;  // (2*64-1)^2

// bias[h][n][m] = table[((n-32)*128 + (m-32) + 64) mod 16129][h]
__global__ __launch_bounds__(256)
void bias_precompute_kernel(const float* __restrict__ table,
                            float* __restrict__ bias) {
  int t = blockIdx.x * 256 + threadIdx.x;
  if (t >= kH * kM * kM) return;
  int h = t >> 12;
  int n = (t >> 6) & 63;
  int m = t & 63;
  int idx = n * 128 + m - 4064;   // (n-32)*128 + (m-32) + 64
  if (idx < 0) idx += kTableRows; // python % wrap
  bias[t] = table[idx * kH + h];
}

template <bool kUseBiasWs>
__global__ __launch_bounds__(64)
void attn_kernel(const float* __restrict__ q, const float* __restrict__ k,
                 const float* __restrict__ v, const float* __restrict__ bias,
                 const float* __restrict__ table, float* __restrict__ out) {
  const int bh = blockIdx.x;        // b*8 + h
  const int b = bh >> 3;
  const int h = bh & 7;
  const int n = threadIdx.x;        // query row owned by this lane

  const float* qp = q + (size_t)bh * (kM * kD) + n * kD;
  const float* kp = k + (size_t)bh * (kM * kD);
  const float* vp = v + (size_t)bh * (kM * kD);

  // Q row -> registers (per-lane contiguous float4 loads)
  float qr[kD];
#pragma unroll
  for (int d4 = 0; d4 < kD / 4; ++d4) {
    float4 t = reinterpret_cast<const float4*>(qp)[d4];
    qr[4 * d4 + 0] = t.x; qr[4 * d4 + 1] = t.y;
    qr[4 * d4 + 2] = t.z; qr[4 * d4 + 3] = t.w;
  }

  // ---- S = Q . K^T  (K rows are wave-uniform -> scalar loads, SGPR bcast)
  float s[kM];
  for (int m = 0; m < kM; ++m) {
    const float* kr = kp + m * kD;  // uniform across lanes
    float a0 = 0.f, a1 = 0.f, a2 = 0.f, a3 = 0.f;
#pragma unroll
    for (int d = 0; d < kD; d += 4) {
      a0 = fmaf(qr[d + 0], kr[d + 0], a0);
      a1 = fmaf(qr[d + 1], kr[d + 1], a1);
      a2 = fmaf(qr[d + 2], kr[d + 2], a2);
      a3 = fmaf(qr[d + 3], kr[d + 3], a3);
    }
    s[m] = (a0 + a1) + (a2 + a3);
  }

  // ---- scale + bias
  constexpr float kScale = 0.125f;  // 64^-0.5
  if (kUseBiasWs) {
    const float* bp = bias + h * (kM * kM) + n * kM;
#pragma unroll
    for (int m4 = 0; m4 < kM / 4; ++m4) {
      float4 t = reinterpret_cast<const float4*>(bp)[m4];
      s[4 * m4 + 0] = fmaf(s[4 * m4 + 0], kScale, t.x);
      s[4 * m4 + 1] = fmaf(s[4 * m4 + 1], kScale, t.y);
      s[4 * m4 + 2] = fmaf(s[4 * m4 + 2], kScale, t.z);
      s[4 * m4 + 3] = fmaf(s[4 * m4 + 3], kScale, t.w);
    }
  } else {
    for (int m = 0; m < kM; ++m) {
      int idx = n * 128 + m - 4064;
      if (idx < 0) idx += kTableRows;
      s[m] = fmaf(s[m], kScale, table[idx * kH + h]);
    }
  }

  // ---- softmax over m (fully in-lane)
  float mx0 = s[0], mx1 = s[1], mx2 = s[2], mx3 = s[3];
#pragma unroll
  for (int m = 4; m < kM; m += 4) {
    mx0 = fmaxf(mx0, s[m + 0]); mx1 = fmaxf(mx1, s[m + 1]);
    mx2 = fmaxf(mx2, s[m + 2]); mx3 = fmaxf(mx3, s[m + 3]);
  }
  const float mx = fmaxf(fmaxf(mx0, mx1), fmaxf(mx2, mx3));
  float sm0 = 0.f, sm1 = 0.f, sm2 = 0.f, sm3 = 0.f;
#pragma unroll
  for (int m = 0; m < kM; m += 4) {
    s[m + 0] = __expf(s[m + 0] - mx); sm0 += s[m + 0];
    s[m + 1] = __expf(s[m + 1] - mx); sm1 += s[m + 1];
    s[m + 2] = __expf(s[m + 2] - mx); sm2 += s[m + 2];
    s[m + 3] = __expf(s[m + 3] - mx); sm3 += s[m + 3];
  }
  const float inv = 1.0f / ((sm0 + sm1) + (sm2 + sm3));

  // ---- O = P . V  (V rows wave-uniform -> scalar loads; 64 indep accums)
  float o[kD];
#pragma unroll
  for (int d = 0; d < kD; ++d) o[d] = 0.f;
  for (int m = 0; m < kM; ++m) {
    const float* vr = vp + m * kD;  // uniform across lanes
    const float p = s[m];
#pragma unroll
    for (int d = 0; d < kD; ++d) o[d] = fmaf(p, vr[d], o[d]);
  }

  // ---- epilogue: transpose+reshape+roll folded into the store index.
  // attn_out(b, h, n, d) -> out[b*32768 + n*512 + ((h*64 + d - 32) & 511)]
  float* op = out + (size_t)b * (kM * kH * kD) + n * (kH * kD);
#pragma unroll
  for (int d4 = 0; d4 < kD / 4; ++d4) {
    const int c = (h * kD + 4 * d4 + 480) & 511;  // (h*64 + d - 32) mod 512
    float4 t;
    t.x = o[4 * d4 + 0] * inv;
    t.y = o[4 * d4 + 1] * inv;
    t.z = o[4 * d4 + 2] * inv;
    t.w = o[4 * d4 + 3] * inv;
    *reinterpret_cast<float4*>(op + c) = t;
  }
}

}  // namespace

extern "C" void kernel_launch(void* const* d_in, const int* in_sizes, int n_in,
                              void* d_out, int out_size, void* d_ws, size_t ws_size,
                              hipStream_t stream) {
  const float* q = (const float*)d_in[0];
  const float* k = (const float*)d_in[1];
  const float* v = (const float*)d_in[2];
  const float* table = (const float*)d_in[3];
  float* out = (float*)d_out;

  const size_t bias_bytes = (size_t)kH * kM * kM * sizeof(float);  // 128 KiB
  if (d_ws != nullptr && ws_size >= bias_bytes) {
    float* bias = (float*)d_ws;
    bias_precompute_kernel<<<(kH * kM * kM + 255) / 256, 256, 0, stream>>>(
        table, bias);
    attn_kernel<true><<<kB * kH, 64, 0, stream>>>(q, k, v, bias, table, out);
  } else {
    attn_kernel<false><<<kB * kH, 64, 0, stream>>>(q, k, v, nullptr, table,
                                                   out);
  }
}